// Round 1
// baseline (519.475 us; speedup 1.0000x reference)
//
#include <hip/hip_runtime.h>
#include <hip/hip_bf16.h>

#define N_ATOMS 32768
#define N_EDGESC 262144
#define ATOM_F 256
#define EDGE_F 128
#define OUT_F 512
#define N_GAUSS 50
#define IN_F 690
#define KPAD 704
#define NCHUNK 11

#define BM 128
#define BN 128
#define NTHREADS 256

using f32x4  = __attribute__((ext_vector_type(4))) float;
using short8 = __attribute__((ext_vector_type(8))) short;

__device__ __forceinline__ unsigned short f2bf(float f) {
  unsigned int u = __builtin_bit_cast(unsigned int, f);
  u += 0x7fffu + ((u >> 16) & 1u);   // round-to-nearest-even
  return (unsigned short)(u >> 16);
}

// ---- detect int64 vs int32 edge_index (deterministic, data-driven) ----
__global__ void detect_idx_kernel(const unsigned int* __restrict__ ei, int* __restrict__ flag) {
  if (threadIdx.x == 0) {
    int ok = 1;
    for (int i = 0; i < 64; ++i) {
      unsigned int lo = ei[2 * i], hi = ei[2 * i + 1];
      if (hi != 0u || lo >= (unsigned)N_ATOMS) { ok = 0; break; }
    }
    *flag = ok;  // 1 => int64 layout
  }
}

// ---- W (512x690 fp32, row-major [n][k]) -> Wbt (512x704 bf16, zero-padded k) ----
__global__ void prep_w_kernel(const float* __restrict__ W, unsigned short* __restrict__ Wbt) {
  int n = blockIdx.x;
  for (int k = threadIdx.x; k < KPAD; k += blockDim.x) {
    float v = (k < IN_F) ? W[n * IN_F + k] : 0.0f;
    Wbt[n * KPAD + k] = f2bf(v);
  }
}

// ---- fused gather + gaussian + GEMM ----
__global__ __launch_bounds__(NTHREADS, 2) void gemm_kernel(
    const float* __restrict__ h, const float* __restrict__ m,
    const float* __restrict__ magft, const void* __restrict__ ei,
    const int* __restrict__ flagp, const unsigned short* __restrict__ Wbt,
    float* __restrict__ out)
{
  __shared__ __align__(16) unsigned short As[BM * 64];  // 16 KB, XOR-swizzled
  __shared__ __align__(16) unsigned short Bs[BN * 64];  // 16 KB, XOR-swizzled
  __shared__ int sIdx[BM], tIdx[BM];

  const int tid = threadIdx.x;
  const int nb  = blockIdx.x * BN;   // 0..3 * 128
  const int eb  = blockIdx.y * BM;   // edge block

  const int use64 = *flagp;
  if (tid < BM) {
    int e = eb + tid;
    if (use64) {
      const long long* p = (const long long*)ei;
      sIdx[tid] = (int)p[e];
      tIdx[tid] = (int)p[N_EDGESC + e];
    } else {
      const int* p = (const int*)ei;
      sIdx[tid] = p[e];
      tIdx[tid] = p[N_EDGESC + e];
    }
  }
  __syncthreads();

  const int lane = tid & 63;
  const int wid  = tid >> 6;     // 0..3
  const int wr   = wid >> 1;     // M half
  const int wc   = wid & 1;      // N half

  f32x4 acc[4][4];
#pragma unroll
  for (int i = 0; i < 4; ++i)
#pragma unroll
    for (int j = 0; j < 4; ++j) acc[i][j] = (f32x4){0.f, 0.f, 0.f, 0.f};

  const int ar = tid >> 1;   // A staging row 0..127
  const int ah = tid & 1;    // A staging half

  for (int kc = 0; kc < NCHUNK; ++kc) {
    // ---------- stage A chunk [128 rows][64 bf16] ----------
    if (kc < 10) {
      const float* p;
      if (kc < 8) {
        int atom = (kc < 4) ? sIdx[ar] : tIdx[ar];
        p = h + (size_t)atom * ATOM_F + (kc & 3) * 64 + ah * 32;
      } else {
        p = m + (size_t)(eb + ar) * EDGE_F + (kc & 1) * 64 + ah * 32;
      }
      float4 v[8];
#pragma unroll
      for (int j = 0; j < 8; ++j) v[j] = ((const float4*)p)[j];
      unsigned int u[16];
#pragma unroll
      for (int j = 0; j < 8; ++j) {
        u[2 * j]     = (unsigned)f2bf(v[j].x) | ((unsigned)f2bf(v[j].y) << 16);
        u[2 * j + 1] = (unsigned)f2bf(v[j].z) | ((unsigned)f2bf(v[j].w) << 16);
      }
      char* base = (char*)As + ar * 128;
#pragma unroll
      for (int j = 0; j < 4; ++j) {
        int colb = ah * 64 + j * 16;
        *(uint4*)(base + (colb ^ ((ar & 7) << 4))) =
            make_uint4(u[4 * j], u[4 * j + 1], u[4 * j + 2], u[4 * j + 3]);
      }
    } else {
      // gaussian smearing chunk: cols 640..689 valid, 690..703 zero
      if (tid < BM) {
        int r = tid;
        int s = sIdx[r], tg = tIdx[r];
        float ax = magft[3 * s], ay = magft[3 * s + 1], az = magft[3 * s + 2];
        float bx = magft[3 * tg], by = magft[3 * tg + 1], bz = magft[3 * tg + 2];
        float d = ax * bx + ay * by + az * bz;
        const float step  = 3.0f / 49.0f;
        const float coeff = -0.5f / (step * step);
        unsigned int u[32];
#pragma unroll
        for (int g2 = 0; g2 < 32; ++g2) {
          float olo = -1.5f + step * (float)(2 * g2);
          float ohi = -1.5f + step * (float)(2 * g2 + 1);
          float vlo = (2 * g2     < N_GAUSS) ? __expf(coeff * (d - olo) * (d - olo)) : 0.0f;
          float vhi = (2 * g2 + 1 < N_GAUSS) ? __expf(coeff * (d - ohi) * (d - ohi)) : 0.0f;
          u[g2] = (unsigned)f2bf(vlo) | ((unsigned)f2bf(vhi) << 16);
        }
        char* base = (char*)As + r * 128;
#pragma unroll
        for (int j = 0; j < 8; ++j) {
          *(uint4*)(base + ((j * 16) ^ ((r & 7) << 4))) =
              make_uint4(u[4 * j], u[4 * j + 1], u[4 * j + 2], u[4 * j + 3]);
        }
      }
    }

    // ---------- stage B chunk [128 n-rows][64 bf16] from pre-cvt Wbt ----------
    {
      int r = tid >> 1, hf = tid & 1;
      const uint4* wp = (const uint4*)(Wbt + (size_t)(nb + r) * KPAD + kc * 64 + hf * 32);
      char* base = (char*)Bs + r * 128;
#pragma unroll
      for (int j = 0; j < 4; ++j) {
        uint4 v = wp[j];
        *(uint4*)(base + ((hf * 64 + j * 16) ^ ((r & 7) << 4))) = v;
      }
    }
    __syncthreads();

    // ---------- compute: 2 k-slices of 32 ----------
#pragma unroll
    for (int ks = 0; ks < 2; ++ks) {
      short8 a[4], b[4];
#pragma unroll
      for (int mi = 0; mi < 4; ++mi) {
        int row  = wr * 64 + mi * 16 + (lane & 15);
        int colb = ks * 64 + ((lane >> 4) << 4);
        a[mi] = *(const short8*)((const char*)As + row * 128 + (colb ^ ((row & 7) << 4)));
      }
#pragma unroll
      for (int ni = 0; ni < 4; ++ni) {
        int row  = wc * 64 + ni * 16 + (lane & 15);
        int colb = ks * 64 + ((lane >> 4) << 4);
        b[ni] = *(const short8*)((const char*)Bs + row * 128 + (colb ^ ((row & 7) << 4)));
      }
#pragma unroll
      for (int mi = 0; mi < 4; ++mi)
#pragma unroll
        for (int ni = 0; ni < 4; ++ni)
          acc[mi][ni] = __builtin_amdgcn_mfma_f32_16x16x32_bf16(a[mi], b[ni], acc[mi][ni], 0, 0, 0);
    }
    __syncthreads();
  }

  // ---------- epilogue: C/D layout col=lane&15, row=(lane>>4)*4+reg ----------
#pragma unroll
  for (int mi = 0; mi < 4; ++mi) {
    int row0 = eb + wr * 64 + mi * 16 + ((lane >> 4) << 2);
#pragma unroll
    for (int ni = 0; ni < 4; ++ni) {
      int col = nb + wc * 64 + ni * 16 + (lane & 15);
#pragma unroll
      for (int j = 0; j < 4; ++j) {
        out[(size_t)(row0 + j) * OUT_F + col] = acc[mi][ni][j];
      }
    }
  }
}

extern "C" void kernel_launch(void* const* d_in, const int* in_sizes, int n_in,
                              void* d_out, int out_size, void* d_ws, size_t ws_size,
                              hipStream_t stream) {
  const float* h     = (const float*)d_in[0];
  const float* m     = (const float*)d_in[1];
  const float* magft = (const float*)d_in[2];
  const void*  ei    = d_in[3];
  const float* W     = (const float*)d_in[4];
  float* out = (float*)d_out;

  char* ws = (char*)d_ws;
  int* flag = (int*)ws;
  unsigned short* Wbt = (unsigned short*)(ws + 256);  // 512*704*2 = 720896 B

  detect_idx_kernel<<<1, 64, 0, stream>>>((const unsigned int*)ei, flag);
  prep_w_kernel<<<OUT_F, 256, 0, stream>>>(W, Wbt);

  dim3 grid(OUT_F / BN, N_EDGESC / BM);
  gemm_kernel<<<grid, NTHREADS, 0, stream>>>(h, m, magft, ei, flag, Wbt, out);
}

// Round 2
// 311.688 us; speedup vs baseline: 1.6666x; 1.6666x over previous
//
#include <hip/hip_runtime.h>
#include <hip/hip_bf16.h>

#define N_ATOMS 32768
#define N_EDGESC 262144
#define ATOM_F 256
#define EDGE_F 128
#define OUT_F 512
#define N_GAUSS 50
#define IN_F 690
#define NCHUNK 11

#define BM 128
#define BN 512
#define NTHREADS 512

using f32x4  = __attribute__((ext_vector_type(4))) float;
using short8 = __attribute__((ext_vector_type(8))) short;

__device__ __forceinline__ unsigned short f2bf(float f) {
  unsigned int u = __builtin_bit_cast(unsigned int, f);
  u += 0x7fffu + ((u >> 16) & 1u);   // round-to-nearest-even
  return (unsigned short)(u >> 16);
}

// ---- detect int64 vs int32 edge_index (deterministic, data-driven) ----
__global__ void detect_idx_kernel(const unsigned int* __restrict__ ei, int* __restrict__ flag) {
  if (threadIdx.x == 0) {
    int ok = 1;
    for (int i = 0; i < 64; ++i) {
      unsigned int lo = ei[2 * i], hi = ei[2 * i + 1];
      if (hi != 0u || lo >= (unsigned)N_ATOMS) { ok = 0; break; }
    }
    *flag = ok;  // 1 => int64 layout
  }
}

// ---- W (512x690 fp32 [n][k]) -> Wp bf16 in MFMA-fragment order ----
// Fragment (kc, ks, nt): 64 lanes x 16B contiguous (1 KB).
// lane l holds B[n = nt*16 + (l&15)][k = kc*64 + ks*32 + (l>>4)*8 + j], j=0..7
// Total: 11*2*32 frags * 1 KB = 704 KB.
__global__ void prep_w_kernel(const float* __restrict__ W, unsigned short* __restrict__ Wp) {
  int g = blockIdx.x * blockDim.x + threadIdx.x;   // one thread per fragment-lane
  if (g >= NCHUNK * 2 * 32 * 64) return;
  int l  = g & 63;
  int nt = (g >> 6) & 31;
  int ks = (g >> 11) & 1;
  int kc = g >> 12;
  int n  = nt * 16 + (l & 15);
  int k0 = kc * 64 + ks * 32 + ((l >> 4) << 3);
  unsigned int u[4];
#pragma unroll
  for (int p = 0; p < 4; ++p) {
    int ka = k0 + 2 * p, kb = k0 + 2 * p + 1;
    float va = (ka < IN_F) ? W[n * IN_F + ka] : 0.0f;
    float vb = (kb < IN_F) ? W[n * IN_F + kb] : 0.0f;
    u[p] = (unsigned)f2bf(va) | ((unsigned)f2bf(vb) << 16);
  }
  *(uint4*)(Wp + (size_t)g * 8) = make_uint4(u[0], u[1], u[2], u[3]);
}

// ---- fused gather + gaussian + GEMM, BN = full 512 ----
__global__ __launch_bounds__(NTHREADS, 2) void gemm_kernel(
    const float* __restrict__ h, const float* __restrict__ m,
    const float* __restrict__ magft, const void* __restrict__ ei,
    const int* __restrict__ flagp, const unsigned short* __restrict__ Wp,
    float* __restrict__ out)
{
  __shared__ __align__(16) unsigned short As[2][BM * 64];  // 2 x 16 KB, XOR-swizzled
  __shared__ int sIdx[BM], tIdx[BM];
  __shared__ float dLDS[BM];

  const int tid = threadIdx.x;
  const int eb  = blockIdx.x * BM;

  const int use64 = *flagp;
  if (tid < BM) {
    int e = eb + tid;
    int s, tg;
    if (use64) {
      const long long* p = (const long long*)ei;
      s  = (int)p[e];
      tg = (int)p[N_EDGESC + e];
    } else {
      const int* p = (const int*)ei;
      s  = p[e];
      tg = p[N_EDGESC + e];
    }
    sIdx[tid] = s;
    tIdx[tid] = tg;
    float ax = magft[3 * s],  ay = magft[3 * s + 1],  az = magft[3 * s + 2];
    float bx = magft[3 * tg], by = magft[3 * tg + 1], bz = magft[3 * tg + 2];
    dLDS[tid] = ax * bx + ay * by + az * bz;
  }
  __syncthreads();

  const int lane = tid & 63;
  const int wid  = tid >> 6;     // 0..7
  const int wr   = wid >> 2;     // M half (0..1)
  const int wc   = wid & 3;      // N quarter (0..3)

  const int ar = tid >> 2;       // staging row 0..127
  const int aq = tid & 3;        // staging quarter (16 cols)

  // ---- A-chunk staging: [128 rows][64 bf16], swizzled ----
  auto stageA = [&](int kchunk, int buf) {
    char* base = (char*)&As[buf][0] + ar * 128;
    const int sw = (ar & 7) << 4;
    if (kchunk < 10) {
      const float* p;
      if (kchunk < 8) {
        int atom = (kchunk < 4) ? sIdx[ar] : tIdx[ar];
        p = h + (size_t)atom * ATOM_F + (kchunk & 3) * 64 + aq * 16;
      } else {
        p = m + (size_t)(eb + ar) * EDGE_F + (kchunk & 1) * 64 + aq * 16;
      }
      float4 v[4];
#pragma unroll
      for (int j = 0; j < 4; ++j) v[j] = ((const float4*)p)[j];
      unsigned int u[8];
#pragma unroll
      for (int j = 0; j < 4; ++j) {
        u[2 * j]     = (unsigned)f2bf(v[j].x) | ((unsigned)f2bf(v[j].y) << 16);
        u[2 * j + 1] = (unsigned)f2bf(v[j].z) | ((unsigned)f2bf(v[j].w) << 16);
      }
      *(uint4*)(base + ((aq * 32)      ^ sw)) = make_uint4(u[0], u[1], u[2], u[3]);
      *(uint4*)(base + ((aq * 32 + 16) ^ sw)) = make_uint4(u[4], u[5], u[6], u[7]);
    } else {
      // gaussian chunk: within-chunk cols 0..49 valid, 50..63 zero
      float d = dLDS[ar];
      const float step  = 3.0f / 49.0f;
      const float coeff = -0.5f / (step * step);
      unsigned int u[8];
#pragma unroll
      for (int p2 = 0; p2 < 8; ++p2) {
        int c0 = aq * 16 + 2 * p2, c1 = c0 + 1;
        float o0 = -1.5f + step * (float)c0;
        float o1 = -1.5f + step * (float)c1;
        float v0 = (c0 < N_GAUSS) ? __expf(coeff * (d - o0) * (d - o0)) : 0.0f;
        float v1 = (c1 < N_GAUSS) ? __expf(coeff * (d - o1) * (d - o1)) : 0.0f;
        u[p2] = (unsigned)f2bf(v0) | ((unsigned)f2bf(v1) << 16);
      }
      *(uint4*)(base + ((aq * 32)      ^ sw)) = make_uint4(u[0], u[1], u[2], u[3]);
      *(uint4*)(base + ((aq * 32 + 16) ^ sw)) = make_uint4(u[4], u[5], u[6], u[7]);
    }
  };

  f32x4 acc[4][8];
#pragma unroll
  for (int i = 0; i < 4; ++i)
#pragma unroll
    for (int j = 0; j < 8; ++j) acc[i][j] = (f32x4){0.f, 0.f, 0.f, 0.f};

  stageA(0, 0);
  __syncthreads();

  const short8* Wp8 = (const short8*)Wp;

  for (int kc = 0; kc < NCHUNK; ++kc) {
    const int cur = kc & 1;
    if (kc < NCHUNK - 1) stageA(kc + 1, cur ^ 1);

    const char* abase = (const char*)&As[cur][0];
#pragma unroll
    for (int ks = 0; ks < 2; ++ks) {
      short8 b[8];
#pragma unroll
      for (int ni = 0; ni < 8; ++ni)
        b[ni] = Wp8[(size_t)(((kc * 2 + ks) * 32 + wc * 8 + ni) << 6) + lane];
      short8 a[4];
#pragma unroll
      for (int mi = 0; mi < 4; ++mi) {
        int row = wr * 64 + mi * 16 + (lane & 15);
        int colb = (ks * 64 + ((lane >> 4) << 4)) ^ ((row & 7) << 4);
        a[mi] = *(const short8*)(abase + row * 128 + colb);
      }
#pragma unroll
      for (int mi = 0; mi < 4; ++mi)
#pragma unroll
        for (int ni = 0; ni < 8; ++ni)
          acc[mi][ni] = __builtin_amdgcn_mfma_f32_16x16x32_bf16(a[mi], b[ni], acc[mi][ni], 0, 0, 0);
    }
    if (kc < NCHUNK - 1) __syncthreads();
  }

  // ---- epilogue: C/D layout col=lane&15, row=(lane>>4)*4+j ----
#pragma unroll
  for (int mi = 0; mi < 4; ++mi) {
    int row0 = eb + wr * 64 + mi * 16 + ((lane >> 4) << 2);
#pragma unroll
    for (int ni = 0; ni < 8; ++ni) {
      int col = wc * 128 + ni * 16 + (lane & 15);
#pragma unroll
      for (int j = 0; j < 4; ++j) {
        out[(size_t)(row0 + j) * OUT_F + col] = acc[mi][ni][j];
      }
    }
  }
}

extern "C" void kernel_launch(void* const* d_in, const int* in_sizes, int n_in,
                              void* d_out, int out_size, void* d_ws, size_t ws_size,
                              hipStream_t stream) {
  const float* h     = (const float*)d_in[0];
  const float* m     = (const float*)d_in[1];
  const float* magft = (const float*)d_in[2];
  const void*  ei    = d_in[3];
  const float* W     = (const float*)d_in[4];
  float* out = (float*)d_out;

  char* ws = (char*)d_ws;
  int* flag = (int*)ws;
  unsigned short* Wp = (unsigned short*)(ws + 256);  // 704 KB fragment-packed W

  detect_idx_kernel<<<1, 64, 0, stream>>>((const unsigned int*)ei, flag);
  prep_w_kernel<<<(NCHUNK * 2 * 32 * 64 + 255) / 256, 256, 0, stream>>>(W, Wp);

  gemm_kernel<<<dim3(N_EDGESC / BM), NTHREADS, 0, stream>>>(h, m, magft, ei, flag, Wp, out);
}